// Round 5
// baseline (540.969 us; speedup 1.0000x reference)
//
#include <hip/hip_runtime.h>
#include <math.h>

#define BATCH 8
#define IH 384
#define IW 512
#define NPIX (IH*IW)          // 196608
#define BN (BATCH*NPIX)       // 1572864

// Fused-kernel tiling: 64x16 output tile, +2 halo each side for the 5-tap filter
#define TW 64
#define TH 16
#define RW (TW+4)             // 68
#define RH (TH+4)             // 20
#define RN (RW*RH)            // 1360
#define NTX (IW/TW)           // 8
#define NTY (IH/TH)           // 24
#define NB_DIR (NTX*NTY*BATCH*2)   // 3072

#define NB_FLOW 1536
#define ENT_OFF NB_DIR                 // 3072
#define EPE_OFF (ENT_OFF + NB_FLOW)    // 4608
#define PART_FLOATS 8192

__device__ __forceinline__ float frcp_(float x){ return __builtin_amdgcn_rcpf(x); }
__device__ __forceinline__ float fsqrt_(float x){ return __builtin_amdgcn_sqrtf(x); }
__device__ __forceinline__ float sigmoidf_(float x){ return frcp_(1.0f + __expf(-x)); }

__device__ __forceinline__ float block_reduce_sum(float v){
    __shared__ float s[8];
    #pragma unroll
    for (int off=32; off>0; off>>=1) v += __shfl_down(v, off);
    int lane = threadIdx.x & 63, wid = threadIdx.x >> 6;
    if (lane==0) s[wid] = v;
    __syncthreads();
    float t = 0.f;
    if (wid==0){
        int nw = (blockDim.x+63)>>6;
        t = (lane < nw) ? s[lane] : 0.f;
        #pragma unroll
        for (int off=4; off>0; off>>=1) t += __shfl_down(t, off);
    }
    __syncthreads();
    return t;
}

// bilinear tap indices/weights; vin=0 zeroes all weights (out-of-image query pixel)
__device__ __forceinline__ void taps_(float Xp, float Yp, float vin, int idx[4], float wt[4]){
    float x0f = floorf(Xp), y0f = floorf(Yp);
    float wx1 = Xp-x0f, wy1 = Yp-y0f, wx0 = 1.f-wx1, wy0 = 1.f-wy1;
    float xs[4] = {x0f, x0f+1.f, x0f,      x0f+1.f};
    float ys[4] = {y0f, y0f,     y0f+1.f,  y0f+1.f};
    float wsx[4] = {wx0*wy0*vin, wx1*wy0*vin, wx0*wy1*vin, wx1*wy1*vin};
    #pragma unroll
    for (int k=0;k<4;++k){
        bool valid = (xs[k]>=0.f) & (xs[k]<=(float)(IW-1)) & (ys[k]>=0.f) & (ys[k]<=(float)(IH-1));
        float xc = fminf(fmaxf(xs[k],0.f),(float)(IW-1));
        float yc = fminf(fmaxf(ys[k],0.f),(float)(IH-1));
        idx[k] = (int)yc*IW + (int)xc;
        wt[k]  = valid ? wsx[k] : 0.f;
    }
}

// Prep: flows = mean + exp(lv/2)*noise (interleaved float2) + entropy/epe partials
//       + repack both images planar->pixel-major float4, all in one pass.
__global__ __launch_bounds__(256)
void prep_kernel(const float* __restrict__ meanf, const float* __restrict__ log_varf,
                 const float* __restrict__ meanb, const float* __restrict__ log_varb,
                 const float* __restrict__ target,
                 const float* __restrict__ noise_f, const float* __restrict__ noise_b,
                 const float* __restrict__ img1, const float* __restrict__ img2,
                 float2* __restrict__ flowf2, float2* __restrict__ flowb2,
                 float4* __restrict__ img4_1, float4* __restrict__ img4_2,
                 float* __restrict__ part)
{
    int t = blockIdx.x*blockDim.x + threadIdx.x;      // float4-group over (B, NPIX/4)
    const int NP4 = NPIX/4;
    int b = t / NP4, p4 = t - b*NP4;
    size_t i0 = ((size_t)b*2*NPIX)/4 + p4;
    size_t i1 = i0 + NP4;

    const float4* mf = (const float4*)meanf;  const float4* lf = (const float4*)log_varf;
    const float4* mb = (const float4*)meanb;  const float4* lb = (const float4*)log_varb;
    const float4* nf = (const float4*)noise_f; const float4* nb = (const float4*)noise_b;
    const float4* tg = (const float4*)target;

    float4 lf0 = lf[i0], lf1 = lf[i1], lb0 = lb[i0], lb1 = lb[i1];
    float4 mf0 = mf[i0], mf1 = mf[i1], mb0 = mb[i0], mb1 = mb[i1];
    float4 nf0 = nf[i0], nf1 = nf[i1], nb0 = nb[i0], nb1 = nb[i1];

    float4 fx, fy;
    fx.x = mf0.x + __expf(0.5f*lf0.x)*nf0.x; fx.y = mf0.y + __expf(0.5f*lf0.y)*nf0.y;
    fx.z = mf0.z + __expf(0.5f*lf0.z)*nf0.z; fx.w = mf0.w + __expf(0.5f*lf0.w)*nf0.w;
    fy.x = mf1.x + __expf(0.5f*lf1.x)*nf1.x; fy.y = mf1.y + __expf(0.5f*lf1.y)*nf1.y;
    fy.z = mf1.z + __expf(0.5f*lf1.z)*nf1.z; fy.w = mf1.w + __expf(0.5f*lf1.w)*nf1.w;
    float2* df = flowf2 + (size_t)b*NPIX + 4*(size_t)p4;
    df[0] = make_float2(fx.x, fy.x); df[1] = make_float2(fx.y, fy.y);
    df[2] = make_float2(fx.z, fy.z); df[3] = make_float2(fx.w, fy.w);

    fx.x = mb0.x + __expf(0.5f*lb0.x)*nb0.x; fx.y = mb0.y + __expf(0.5f*lb0.y)*nb0.y;
    fx.z = mb0.z + __expf(0.5f*lb0.z)*nb0.z; fx.w = mb0.w + __expf(0.5f*lb0.w)*nb0.w;
    fy.x = mb1.x + __expf(0.5f*lb1.x)*nb1.x; fy.y = mb1.y + __expf(0.5f*lb1.y)*nb1.y;
    fy.z = mb1.z + __expf(0.5f*lb1.z)*nb1.z; fy.w = mb1.w + __expf(0.5f*lb1.w)*nb1.w;
    float2* db = flowb2 + (size_t)b*NPIX + 4*(size_t)p4;
    db[0] = make_float2(fx.x, fy.x); db[1] = make_float2(fx.y, fy.y);
    db[2] = make_float2(fx.z, fy.z); db[3] = make_float2(fx.w, fy.w);

    // image repack
    {
        const float4* s1 = (const float4*)(img1 + (size_t)b*3*NPIX);
        float4 c0 = s1[p4], c1 = s1[NP4 + p4], c2 = s1[2*NP4 + p4];
        float4* d1 = img4_1 + (size_t)b*NPIX + 4*(size_t)p4;
        d1[0] = make_float4(c0.x, c1.x, c2.x, 0.f);
        d1[1] = make_float4(c0.y, c1.y, c2.y, 0.f);
        d1[2] = make_float4(c0.z, c1.z, c2.z, 0.f);
        d1[3] = make_float4(c0.w, c1.w, c2.w, 0.f);
        const float4* s2 = (const float4*)(img2 + (size_t)b*3*NPIX);
        c0 = s2[p4]; c1 = s2[NP4 + p4]; c2 = s2[2*NP4 + p4];
        float4* d2 = img4_2 + (size_t)b*NPIX + 4*(size_t)p4;
        d2[0] = make_float4(c0.x, c1.x, c2.x, 0.f);
        d2[1] = make_float4(c0.y, c1.y, c2.y, 0.f);
        d2[2] = make_float4(c0.z, c1.z, c2.z, 0.f);
        d2[3] = make_float4(c0.w, c1.w, c2.w, 0.f);
    }

    float ent = (lf0.x+lf0.y+lf0.z+lf0.w) + (lf1.x+lf1.y+lf1.z+lf1.w)
              + (lb0.x+lb0.y+lb0.z+lb0.w) + (lb1.x+lb1.y+lb1.z+lb1.w);

    float4 t0 = tg[i0], t1 = tg[i1];
    float d0, d1, epe = 0.f;
    d0 = mf0.x - t0.x; d1 = mf1.x - t1.x; epe += fsqrt_(d0*d0 + d1*d1);
    d0 = mf0.y - t0.y; d1 = mf1.y - t1.y; epe += fsqrt_(d0*d0 + d1*d1);
    d0 = mf0.z - t0.z; d1 = mf1.z - t1.z; epe += fsqrt_(d0*d0 + d1*d1);
    d0 = mf0.w - t0.w; d1 = mf1.w - t1.w; epe += fsqrt_(d0*d0 + d1*d1);

    float s = block_reduce_sum(ent);
    if (threadIdx.x == 0) part[ENT_OFF + blockIdx.x] = s;
    float s2 = block_reduce_sum(epe);
    if (threadIdx.x == 0) part[EPE_OFF + blockIdx.x] = s2;
}

// Fused per-direction tile kernel. Branch-free fixed-trip loops:
//  W: warp img_b over tile+halo into 3 LDS planes (6 iters, idempotent tail)
//  T: interior pointwise terms (exactly 4 iters, no divergence)
//  B: gradient-constancy stencil from LDS
__global__ __launch_bounds__(256, 8)
void dir_kernel(const float2* __restrict__ flowf2, const float2* __restrict__ flowb2,
                const float4* __restrict__ img4_1, const float4* __restrict__ img4_2,
                float* __restrict__ part)
{
    __shared__ float wr[RH*RW], wg[RH*RW], wb[RH*RW];   // 3*5440 B
    __shared__ float ml[TH*TW];                          // 4096 B

    // XCD-aware decode: all 192 tiles of one (b,dir) land on one XCD (id%8 heuristic)
    int bx = blockIdx.x;
    int xcd = bx & 7, r = bx >> 3;          // r in [0,384)
    int half = (r >= 192) ? 1 : 0;
    int j = r - half*192;                   // tile in [0,192)
    int t = xcd + (half << 3);              // (b,dir) in [0,16)
    int dir = t & 1, b = t >> 1;
    int tx = j & 7, ty = j >> 3;

    const float2 *pfa, *pfb; const float4 *pia, *pib;
    if (dir == 0){ pfa = flowf2; pfb = flowb2; pia = img4_1; pib = img4_2; }
    else         { pfa = flowb2; pfb = flowf2; pia = img4_2; pib = img4_1; }
    pfa += (size_t)b*NPIX; pfb += (size_t)b*NPIX;
    pia += (size_t)b*NPIX; pib += (size_t)b*NPIX;

    const int tw0 = tx*TW, th0 = ty*TH;
    const int tid = threadIdx.x;
    float local = 0.f;

    // ---- Loop W: halo warp (no accumulation; clamped tail redo is idempotent) ----
    #pragma unroll
    for (int k = 0; k < 6; ++k){
        int i = tid + k*256;
        i = (i < RN) ? i : (RN-1);
        int hh = i / RW, ww = i - hh*RW;
        int gh = th0 + hh - 2, gw = tw0 + ww - 2;
        bool inimg = (gh >= 0) & (gh < IH) & (gw >= 0) & (gw < IW);
        int pc = min(max(gh,0),IH-1)*IW + min(max(gw,0),IW-1);
        float2 fa = pfa[pc];
        float Xp = (float)gw + fa.x, Yp = (float)gh + fa.y;
        int idx[4]; float wt[4];
        taps_(Xp, Yp, inimg ? 1.f : 0.f, idx, wt);
        float4 t0 = pib[idx[0]], t1 = pib[idx[1]], t2 = pib[idx[2]], t3 = pib[idx[3]];
        wr[i] = wt[0]*t0.x + wt[1]*t1.x + wt[2]*t2.x + wt[3]*t3.x;
        wg[i] = wt[0]*t0.y + wt[1]*t1.y + wt[2]*t2.y + wt[3]*t3.y;
        wb[i] = wt[0]*t0.z + wt[1]*t1.z + wt[2]*t2.z + wt[3]*t3.z;
    }
    __syncthreads();

    // ---- Loop T: interior terms (1024 = 4*256, branch-free) ----
    #pragma unroll
    for (int k = 0; k < 4; ++k){
        int i = tid + k*256;                 // [0,1024)
        int hh = i >> 6, ww = i & 63;
        int gh = th0 + hh, gw = tw0 + ww;
        int p = gh*IW + gw;
        float2 fa = pfa[p];                  // L1/L2 hit (loaded in loop W)
        float Xp = (float)gw + fa.x, Yp = (float)gh + fa.y;
        int idx[4]; float wt[4];
        taps_(Xp, Yp, 1.f, idx, wt);

        float2 f0 = pfb[idx[0]], f1 = pfb[idx[1]], f2 = pfb[idx[2]], f3 = pfb[idx[3]];
        float fbwx = wt[0]*f0.x + wt[1]*f1.x + wt[2]*f2.x + wt[3]*f3.x;
        float fbwy = wt[0]*f0.y + wt[1]*f1.y + wt[2]*f2.y + wt[3]*f3.y;

        float mx = sigmoidf_(Xp + 0.5f) * (1.f - sigmoidf_(Xp - ((float)IW - 0.5f)));
        float my = sigmoidf_(Yp + 0.5f) * (1.f - sigmoidf_(Yp - ((float)IH - 0.5f)));
        float bm = mx * my;

        float mag = fa.x*fa.x + fa.y*fa.y + fbwx*fbwx + fbwy*fbwy;
        float dfx = fa.x + fbwx, dfy = fa.y + fbwy;
        float D = dfx*dfx + dfy*dfy;
        float occ = 1.f - sigmoidf_(D - (0.01f*mag + 0.5f));
        float mask = bm * occ;
        ml[i] = mask;

        local += (1.f - mask);                            // mask term
        local += fsqrt_(D + 1e-5f) * mask;                // fb term

        int li = (hh+2)*RW + (ww+2);                      // data term (warp from LDS)
        float4 ia = pia[p];
        float d0 = ia.x - wr[li], d1 = ia.y - wg[li], d2 = ia.z - wb[li];
        local += fsqrt_(d0*d0 + d1*d1 + d2*d2 + 1e-5f) * mask;

        // smoothness: clamp-to-self makes the boundary diff exactly 0
        float2 rr = pfa[(gw < IW-1) ? (p+1)  : p];
        float2 dd = pfa[(gh < IH-1) ? (p+IW) : p];
        float e0 = rr.x - fa.x, e1 = rr.y - fa.y;
        float e2 = dd.x - fa.x, e3 = dd.y - fa.y;
        local += fsqrt_(e0*e0 + e1*e1 + e2*e2 + e3*e3 + 1e-5f);
    }
    __syncthreads();

    // ---- Loop B: gradient-constancy (1024 = 4*256, branch-free) ----
    const float K0 = -1.f/12.f, K1 = 2.f/3.f, K3 = -2.f/3.f, K4 = 1.f/12.f;
    const float4 Z = make_float4(0.f,0.f,0.f,0.f);
    #pragma unroll
    for (int k = 0; k < 4; ++k){
        int i = tid + k*256;
        int hh = i >> 6, ww = i & 63;
        int gh = th0 + hh, gw = tw0 + ww;
        int p = gh*IW + gw;
        int li = (hh+2)*RW + (ww+2);

        float4 axm2 = (gw >= 2)    ? pia[p-2]    : Z;
        float4 axm1 = (gw >= 1)    ? pia[p-1]    : Z;
        float4 axp1 = (gw <= IW-2) ? pia[p+1]    : Z;
        float4 axp2 = (gw <= IW-3) ? pia[p+2]    : Z;
        float4 aym2 = (gh >= 2)    ? pia[p-2*IW] : Z;
        float4 aym1 = (gh >= 1)    ? pia[p-IW]   : Z;
        float4 ayp1 = (gh <= IH-2) ? pia[p+IW]   : Z;
        float4 ayp2 = (gh <= IH-3) ? pia[p+2*IW] : Z;

        float Ct = 0.f, d;
        d = (K0*axm2.x + K1*axm1.x + K3*axp1.x + K4*axp2.x)
          - (K0*wr[li-2] + K1*wr[li-1] + K3*wr[li+1] + K4*wr[li+2]); Ct += d*d;
        d = (K0*axm2.y + K1*axm1.y + K3*axp1.y + K4*axp2.y)
          - (K0*wg[li-2] + K1*wg[li-1] + K3*wg[li+1] + K4*wg[li+2]); Ct += d*d;
        d = (K0*axm2.z + K1*axm1.z + K3*axp1.z + K4*axp2.z)
          - (K0*wb[li-2] + K1*wb[li-1] + K3*wb[li+1] + K4*wb[li+2]); Ct += d*d;
        d = (K0*aym2.x + K1*aym1.x + K3*ayp1.x + K4*ayp2.x)
          - (K0*wr[li-2*RW] + K1*wr[li-RW] + K3*wr[li+RW] + K4*wr[li+2*RW]); Ct += d*d;
        d = (K0*aym2.y + K1*aym1.y + K3*ayp1.y + K4*ayp2.y)
          - (K0*wg[li-2*RW] + K1*wg[li-RW] + K3*wg[li+RW] + K4*wg[li+2*RW]); Ct += d*d;
        d = (K0*aym2.z + K1*aym1.z + K3*ayp1.z + K4*ayp2.z)
          - (K0*wb[li-2*RW] + K1*wb[li-RW] + K3*wb[li+RW] + K4*wb[li+2*RW]); Ct += d*d;

        local += fsqrt_(Ct + 1e-5f) * ml[i];
    }

    float s = block_reduce_sum(local);
    if (tid == 0) part[bx] = s;
}

// Finalize: reduce all partials with one block.
__global__ __launch_bounds__(256)
void finalize_kernel(const float* __restrict__ part, float* __restrict__ out)
{
    float e = 0.f, ent = 0.f, epe = 0.f;
    for (int i = threadIdx.x; i < NB_DIR; i += 256) e += part[i];
    for (int i = threadIdx.x; i < NB_FLOW; i += 256){
        ent += part[ENT_OFF + i];
        epe += part[EPE_OFF + i];
    }
    e   = block_reduce_sum(e);
    ent = block_reduce_sum(ent);
    epe = block_reduce_sum(epe);
    if (threadIdx.x == 0){
        out[0] = e / (float)BATCH - ent / (2.f * (float)BATCH);
        out[1] = epe / ((float)BATCH * (float)NPIX);
    }
}

extern "C" void kernel_launch(void* const* d_in, const int* in_sizes, int n_in,
                              void* d_out, int out_size, void* d_ws, size_t ws_size,
                              hipStream_t stream)
{
    const float* meanf    = (const float*)d_in[0];
    const float* log_varf = (const float*)d_in[1];
    const float* meanb    = (const float*)d_in[2];
    const float* log_varb = (const float*)d_in[3];
    const float* img1     = (const float*)d_in[4];
    const float* img2     = (const float*)d_in[5];
    const float* target   = (const float*)d_in[6];
    const float* noise_f  = (const float*)d_in[7];
    const float* noise_b  = (const float*)d_in[8];

    float*  ws     = (float*)d_ws;
    float*  part   = ws;                               // PART_FLOATS floats
    float2* flowf2 = (float2*)(ws + PART_FLOATS);      // BN float2
    float2* flowb2 = flowf2 + (size_t)BN;              // BN float2
    float4* img4_1 = (float4*)(flowb2 + (size_t)BN);   // BN float4
    float4* img4_2 = img4_1 + (size_t)BN;              // BN float4

    const int threads = 256;

    prep_kernel<<<NB_FLOW, threads, 0, stream>>>(meanf, log_varf, meanb, log_varb,
                                                 target, noise_f, noise_b, img1, img2,
                                                 flowf2, flowb2, img4_1, img4_2, part);

    dir_kernel<<<NB_DIR, threads, 0, stream>>>(flowf2, flowb2, img4_1, img4_2, part);

    finalize_kernel<<<1, threads, 0, stream>>>(part, (float*)d_out);
}

// Round 6
// 375.709 us; speedup vs baseline: 1.4399x; 1.4399x over previous
//
#include <hip/hip_runtime.h>
#include <math.h>

#define BATCH 8
#define IH 384
#define IW 512
#define NPIX (IH*IW)          // 196608
#define BN (BATCH*NPIX)       // 1572864

// Fused-kernel tiling: 64x16 output tile, +2 halo each side for the 5-tap filter
#define TW 64
#define TH 16
#define RW (TW+4)             // 68
#define RH (TH+4)             // 20
#define RN (RW*RH)            // 1360
#define NTX (IW/TW)           // 8
#define NTY (IH/TH)           // 24
#define NB_DIR (NTX*NTY*BATCH*2)   // 3072

#define NB_FLOW 1536
#define ENT_OFF NB_DIR                 // 3072
#define EPE_OFF (ENT_OFF + NB_FLOW)    // 4608
#define PART_FLOATS 8192

__device__ __forceinline__ float frcp_(float x){ return __builtin_amdgcn_rcpf(x); }
__device__ __forceinline__ float fsqrt_(float x){ return __builtin_amdgcn_sqrtf(x); }
__device__ __forceinline__ float sigmoidf_(float x){ return frcp_(1.0f + __expf(-x)); }

__device__ __forceinline__ float block_reduce_sum(float v){
    __shared__ float s[8];
    #pragma unroll
    for (int off=32; off>0; off>>=1) v += __shfl_down(v, off);
    int lane = threadIdx.x & 63, wid = threadIdx.x >> 6;
    if (lane==0) s[wid] = v;
    __syncthreads();
    float t = 0.f;
    if (wid==0){
        int nw = (blockDim.x+63)>>6;
        t = (lane < nw) ? s[lane] : 0.f;
        #pragma unroll
        for (int off=4; off>0; off>>=1) t += __shfl_down(t, off);
    }
    __syncthreads();
    return t;
}

// bilinear tap indices/weights; vin=0 zeroes all weights (out-of-image query pixel)
__device__ __forceinline__ void taps_(float Xp, float Yp, float vin, int idx[4], float wt[4]){
    float x0f = floorf(Xp), y0f = floorf(Yp);
    float wx1 = Xp-x0f, wy1 = Yp-y0f, wx0 = 1.f-wx1, wy0 = 1.f-wy1;
    float xs[4] = {x0f, x0f+1.f, x0f,      x0f+1.f};
    float ys[4] = {y0f, y0f,     y0f+1.f,  y0f+1.f};
    float wsx[4] = {wx0*wy0*vin, wx1*wy0*vin, wx0*wy1*vin, wx1*wy1*vin};
    #pragma unroll
    for (int k=0;k<4;++k){
        bool valid = (xs[k]>=0.f) & (xs[k]<=(float)(IW-1)) & (ys[k]>=0.f) & (ys[k]<=(float)(IH-1));
        float xc = fminf(fmaxf(xs[k],0.f),(float)(IW-1));
        float yc = fminf(fmaxf(ys[k],0.f),(float)(IH-1));
        idx[k] = (int)yc*IW + (int)xc;
        wt[k]  = valid ? wsx[k] : 0.f;
    }
}

// Prep: flows = mean + exp(lv/2)*noise (interleaved float2) + entropy/epe partials
//       + repack both images planar->pixel-major float4, all in one pass.
__global__ __launch_bounds__(256)
void prep_kernel(const float* __restrict__ meanf, const float* __restrict__ log_varf,
                 const float* __restrict__ meanb, const float* __restrict__ log_varb,
                 const float* __restrict__ target,
                 const float* __restrict__ noise_f, const float* __restrict__ noise_b,
                 const float* __restrict__ img1, const float* __restrict__ img2,
                 float2* __restrict__ flowf2, float2* __restrict__ flowb2,
                 float4* __restrict__ img4_1, float4* __restrict__ img4_2,
                 float* __restrict__ part)
{
    int t = blockIdx.x*blockDim.x + threadIdx.x;      // float4-group over (B, NPIX/4)
    const int NP4 = NPIX/4;
    int b = t / NP4, p4 = t - b*NP4;
    size_t i0 = ((size_t)b*2*NPIX)/4 + p4;
    size_t i1 = i0 + NP4;

    const float4* mf = (const float4*)meanf;  const float4* lf = (const float4*)log_varf;
    const float4* mb = (const float4*)meanb;  const float4* lb = (const float4*)log_varb;
    const float4* nf = (const float4*)noise_f; const float4* nb = (const float4*)noise_b;
    const float4* tg = (const float4*)target;

    float4 lf0 = lf[i0], lf1 = lf[i1], lb0 = lb[i0], lb1 = lb[i1];
    float4 mf0 = mf[i0], mf1 = mf[i1], mb0 = mb[i0], mb1 = mb[i1];
    float4 nf0 = nf[i0], nf1 = nf[i1], nb0 = nb[i0], nb1 = nb[i1];

    float4 fx, fy;
    fx.x = mf0.x + __expf(0.5f*lf0.x)*nf0.x; fx.y = mf0.y + __expf(0.5f*lf0.y)*nf0.y;
    fx.z = mf0.z + __expf(0.5f*lf0.z)*nf0.z; fx.w = mf0.w + __expf(0.5f*lf0.w)*nf0.w;
    fy.x = mf1.x + __expf(0.5f*lf1.x)*nf1.x; fy.y = mf1.y + __expf(0.5f*lf1.y)*nf1.y;
    fy.z = mf1.z + __expf(0.5f*lf1.z)*nf1.z; fy.w = mf1.w + __expf(0.5f*lf1.w)*nf1.w;
    float2* df = flowf2 + (size_t)b*NPIX + 4*(size_t)p4;
    df[0] = make_float2(fx.x, fy.x); df[1] = make_float2(fx.y, fy.y);
    df[2] = make_float2(fx.z, fy.z); df[3] = make_float2(fx.w, fy.w);

    fx.x = mb0.x + __expf(0.5f*lb0.x)*nb0.x; fx.y = mb0.y + __expf(0.5f*lb0.y)*nb0.y;
    fx.z = mb0.z + __expf(0.5f*lb0.z)*nb0.z; fx.w = mb0.w + __expf(0.5f*lb0.w)*nb0.w;
    fy.x = mb1.x + __expf(0.5f*lb1.x)*nb1.x; fy.y = mb1.y + __expf(0.5f*lb1.y)*nb1.y;
    fy.z = mb1.z + __expf(0.5f*lb1.z)*nb1.z; fy.w = mb1.w + __expf(0.5f*lb1.w)*nb1.w;
    float2* db = flowb2 + (size_t)b*NPIX + 4*(size_t)p4;
    db[0] = make_float2(fx.x, fy.x); db[1] = make_float2(fx.y, fy.y);
    db[2] = make_float2(fx.z, fy.z); db[3] = make_float2(fx.w, fy.w);

    // image repack
    {
        const float4* s1 = (const float4*)(img1 + (size_t)b*3*NPIX);
        float4 c0 = s1[p4], c1 = s1[NP4 + p4], c2 = s1[2*NP4 + p4];
        float4* d1 = img4_1 + (size_t)b*NPIX + 4*(size_t)p4;
        d1[0] = make_float4(c0.x, c1.x, c2.x, 0.f);
        d1[1] = make_float4(c0.y, c1.y, c2.y, 0.f);
        d1[2] = make_float4(c0.z, c1.z, c2.z, 0.f);
        d1[3] = make_float4(c0.w, c1.w, c2.w, 0.f);
        const float4* s2 = (const float4*)(img2 + (size_t)b*3*NPIX);
        c0 = s2[p4]; c1 = s2[NP4 + p4]; c2 = s2[2*NP4 + p4];
        float4* d2 = img4_2 + (size_t)b*NPIX + 4*(size_t)p4;
        d2[0] = make_float4(c0.x, c1.x, c2.x, 0.f);
        d2[1] = make_float4(c0.y, c1.y, c2.y, 0.f);
        d2[2] = make_float4(c0.z, c1.z, c2.z, 0.f);
        d2[3] = make_float4(c0.w, c1.w, c2.w, 0.f);
    }

    float ent = (lf0.x+lf0.y+lf0.z+lf0.w) + (lf1.x+lf1.y+lf1.z+lf1.w)
              + (lb0.x+lb0.y+lb0.z+lb0.w) + (lb1.x+lb1.y+lb1.z+lb1.w);

    float4 t0 = tg[i0], t1 = tg[i1];
    float d0, d1, epe = 0.f;
    d0 = mf0.x - t0.x; d1 = mf1.x - t1.x; epe += fsqrt_(d0*d0 + d1*d1);
    d0 = mf0.y - t0.y; d1 = mf1.y - t1.y; epe += fsqrt_(d0*d0 + d1*d1);
    d0 = mf0.z - t0.z; d1 = mf1.z - t1.z; epe += fsqrt_(d0*d0 + d1*d1);
    d0 = mf0.w - t0.w; d1 = mf1.w - t1.w; epe += fsqrt_(d0*d0 + d1*d1);

    float s = block_reduce_sum(ent);
    if (threadIdx.x == 0) part[ENT_OFF + blockIdx.x] = s;
    float s2 = block_reduce_sum(epe);
    if (threadIdx.x == 0) part[EPE_OFF + blockIdx.x] = s2;
}

// Fused per-direction tile kernel. Branch-free fixed-trip loops.
// __launch_bounds__(256,4): VGPR cap 128 — natural allocation ~48-64, NO SPILL.
// (256,8) in R5 forced VGPR<=64 -> compiler spilled ~180B/thread to scratch:
// WRITE_SIZE 574MB, 3.3x slowdown. Never cap below natural working set.
__global__ __launch_bounds__(256, 4)
void dir_kernel(const float2* __restrict__ flowf2, const float2* __restrict__ flowb2,
                const float4* __restrict__ img4_1, const float4* __restrict__ img4_2,
                float* __restrict__ part)
{
    __shared__ float wr[RH*RW], wg[RH*RW], wb[RH*RW];   // 3*5440 B
    __shared__ float ml[TH*TW];                          // 4096 B

    // XCD-aware decode: all 192 tiles of one (b,dir) land on one XCD (id%8 heuristic)
    int bx = blockIdx.x;
    int xcd = bx & 7, r = bx >> 3;          // r in [0,384)
    int half = (r >= 192) ? 1 : 0;
    int j = r - half*192;                   // tile in [0,192)
    int t = xcd + (half << 3);              // (b,dir) in [0,16)
    int dir = t & 1, b = t >> 1;
    int tx = j & 7, ty = j >> 3;

    const float2 *pfa, *pfb; const float4 *pia, *pib;
    if (dir == 0){ pfa = flowf2; pfb = flowb2; pia = img4_1; pib = img4_2; }
    else         { pfa = flowb2; pfb = flowf2; pia = img4_2; pib = img4_1; }
    pfa += (size_t)b*NPIX; pfb += (size_t)b*NPIX;
    pia += (size_t)b*NPIX; pib += (size_t)b*NPIX;

    const int tw0 = tx*TW, th0 = ty*TH;
    const int tid = threadIdx.x;
    float local = 0.f;

    // ---- Loop W: halo warp (no accumulation; clamped tail redo is idempotent) ----
    #pragma unroll
    for (int k = 0; k < 6; ++k){
        int i = tid + k*256;
        i = (i < RN) ? i : (RN-1);
        int hh = i / RW, ww = i - hh*RW;
        int gh = th0 + hh - 2, gw = tw0 + ww - 2;
        bool inimg = (gh >= 0) & (gh < IH) & (gw >= 0) & (gw < IW);
        int pc = min(max(gh,0),IH-1)*IW + min(max(gw,0),IW-1);
        float2 fa = pfa[pc];
        float Xp = (float)gw + fa.x, Yp = (float)gh + fa.y;
        int idx[4]; float wt[4];
        taps_(Xp, Yp, inimg ? 1.f : 0.f, idx, wt);
        float4 t0 = pib[idx[0]], t1 = pib[idx[1]], t2 = pib[idx[2]], t3 = pib[idx[3]];
        wr[i] = wt[0]*t0.x + wt[1]*t1.x + wt[2]*t2.x + wt[3]*t3.x;
        wg[i] = wt[0]*t0.y + wt[1]*t1.y + wt[2]*t2.y + wt[3]*t3.y;
        wb[i] = wt[0]*t0.z + wt[1]*t1.z + wt[2]*t2.z + wt[3]*t3.z;
    }
    __syncthreads();

    // ---- Loop T: interior terms (1024 = 4*256, branch-free) ----
    #pragma unroll
    for (int k = 0; k < 4; ++k){
        int i = tid + k*256;                 // [0,1024)
        int hh = i >> 6, ww = i & 63;
        int gh = th0 + hh, gw = tw0 + ww;
        int p = gh*IW + gw;
        float2 fa = pfa[p];                  // L1/L2 hit (loaded in loop W)
        float Xp = (float)gw + fa.x, Yp = (float)gh + fa.y;
        int idx[4]; float wt[4];
        taps_(Xp, Yp, 1.f, idx, wt);

        float2 f0 = pfb[idx[0]], f1 = pfb[idx[1]], f2 = pfb[idx[2]], f3 = pfb[idx[3]];
        float fbwx = wt[0]*f0.x + wt[1]*f1.x + wt[2]*f2.x + wt[3]*f3.x;
        float fbwy = wt[0]*f0.y + wt[1]*f1.y + wt[2]*f2.y + wt[3]*f3.y;

        float mx = sigmoidf_(Xp + 0.5f) * (1.f - sigmoidf_(Xp - ((float)IW - 0.5f)));
        float my = sigmoidf_(Yp + 0.5f) * (1.f - sigmoidf_(Yp - ((float)IH - 0.5f)));
        float bm = mx * my;

        float mag = fa.x*fa.x + fa.y*fa.y + fbwx*fbwx + fbwy*fbwy;
        float dfx = fa.x + fbwx, dfy = fa.y + fbwy;
        float D = dfx*dfx + dfy*dfy;
        float occ = 1.f - sigmoidf_(D - (0.01f*mag + 0.5f));
        float mask = bm * occ;
        ml[i] = mask;

        local += (1.f - mask);                            // mask term
        local += fsqrt_(D + 1e-5f) * mask;                // fb term

        int li = (hh+2)*RW + (ww+2);                      // data term (warp from LDS)
        float4 ia = pia[p];
        float d0 = ia.x - wr[li], d1 = ia.y - wg[li], d2 = ia.z - wb[li];
        local += fsqrt_(d0*d0 + d1*d1 + d2*d2 + 1e-5f) * mask;

        // smoothness: clamp-to-self makes the boundary diff exactly 0
        float2 rr = pfa[(gw < IW-1) ? (p+1)  : p];
        float2 dd = pfa[(gh < IH-1) ? (p+IW) : p];
        float e0 = rr.x - fa.x, e1 = rr.y - fa.y;
        float e2 = dd.x - fa.x, e3 = dd.y - fa.y;
        local += fsqrt_(e0*e0 + e1*e1 + e2*e2 + e3*e3 + 1e-5f);
    }
    __syncthreads();

    // ---- Loop B: gradient-constancy (1024 = 4*256, branch-free) ----
    const float K0 = -1.f/12.f, K1 = 2.f/3.f, K3 = -2.f/3.f, K4 = 1.f/12.f;
    const float4 Z = make_float4(0.f,0.f,0.f,0.f);
    #pragma unroll
    for (int k = 0; k < 4; ++k){
        int i = tid + k*256;
        int hh = i >> 6, ww = i & 63;
        int gh = th0 + hh, gw = tw0 + ww;
        int p = gh*IW + gw;
        int li = (hh+2)*RW + (ww+2);

        float4 axm2 = (gw >= 2)    ? pia[p-2]    : Z;
        float4 axm1 = (gw >= 1)    ? pia[p-1]    : Z;
        float4 axp1 = (gw <= IW-2) ? pia[p+1]    : Z;
        float4 axp2 = (gw <= IW-3) ? pia[p+2]    : Z;
        float4 aym2 = (gh >= 2)    ? pia[p-2*IW] : Z;
        float4 aym1 = (gh >= 1)    ? pia[p-IW]   : Z;
        float4 ayp1 = (gh <= IH-2) ? pia[p+IW]   : Z;
        float4 ayp2 = (gh <= IH-3) ? pia[p+2*IW] : Z;

        float Ct = 0.f, d;
        d = (K0*axm2.x + K1*axm1.x + K3*axp1.x + K4*axp2.x)
          - (K0*wr[li-2] + K1*wr[li-1] + K3*wr[li+1] + K4*wr[li+2]); Ct += d*d;
        d = (K0*axm2.y + K1*axm1.y + K3*axp1.y + K4*axp2.y)
          - (K0*wg[li-2] + K1*wg[li-1] + K3*wg[li+1] + K4*wg[li+2]); Ct += d*d;
        d = (K0*axm2.z + K1*axm1.z + K3*axp1.z + K4*axp2.z)
          - (K0*wb[li-2] + K1*wb[li-1] + K3*wb[li+1] + K4*wb[li+2]); Ct += d*d;
        d = (K0*aym2.x + K1*aym1.x + K3*ayp1.x + K4*ayp2.x)
          - (K0*wr[li-2*RW] + K1*wr[li-RW] + K3*wr[li+RW] + K4*wr[li+2*RW]); Ct += d*d;
        d = (K0*aym2.y + K1*aym1.y + K3*ayp1.y + K4*ayp2.y)
          - (K0*wg[li-2*RW] + K1*wg[li-RW] + K3*wg[li+RW] + K4*wg[li+2*RW]); Ct += d*d;
        d = (K0*aym2.z + K1*aym1.z + K3*ayp1.z + K4*ayp2.z)
          - (K0*wb[li-2*RW] + K1*wb[li-RW] + K3*wb[li+RW] + K4*wb[li+2*RW]); Ct += d*d;

        local += fsqrt_(Ct + 1e-5f) * ml[i];
    }

    float s = block_reduce_sum(local);
    if (tid == 0) part[bx] = s;
}

// Finalize: reduce all partials with one block.
__global__ __launch_bounds__(256)
void finalize_kernel(const float* __restrict__ part, float* __restrict__ out)
{
    float e = 0.f, ent = 0.f, epe = 0.f;
    for (int i = threadIdx.x; i < NB_DIR; i += 256) e += part[i];
    for (int i = threadIdx.x; i < NB_FLOW; i += 256){
        ent += part[ENT_OFF + i];
        epe += part[EPE_OFF + i];
    }
    e   = block_reduce_sum(e);
    ent = block_reduce_sum(ent);
    epe = block_reduce_sum(epe);
    if (threadIdx.x == 0){
        out[0] = e / (float)BATCH - ent / (2.f * (float)BATCH);
        out[1] = epe / ((float)BATCH * (float)NPIX);
    }
}

extern "C" void kernel_launch(void* const* d_in, const int* in_sizes, int n_in,
                              void* d_out, int out_size, void* d_ws, size_t ws_size,
                              hipStream_t stream)
{
    const float* meanf    = (const float*)d_in[0];
    const float* log_varf = (const float*)d_in[1];
    const float* meanb    = (const float*)d_in[2];
    const float* log_varb = (const float*)d_in[3];
    const float* img1     = (const float*)d_in[4];
    const float* img2     = (const float*)d_in[5];
    const float* target   = (const float*)d_in[6];
    const float* noise_f  = (const float*)d_in[7];
    const float* noise_b  = (const float*)d_in[8];

    float*  ws     = (float*)d_ws;
    float*  part   = ws;                               // PART_FLOATS floats
    float2* flowf2 = (float2*)(ws + PART_FLOATS);      // BN float2
    float2* flowb2 = flowf2 + (size_t)BN;              // BN float2
    float4* img4_1 = (float4*)(flowb2 + (size_t)BN);   // BN float4
    float4* img4_2 = img4_1 + (size_t)BN;              // BN float4

    const int threads = 256;

    prep_kernel<<<NB_FLOW, threads, 0, stream>>>(meanf, log_varf, meanb, log_varb,
                                                 target, noise_f, noise_b, img1, img2,
                                                 flowf2, flowb2, img4_1, img4_2, part);

    dir_kernel<<<NB_DIR, threads, 0, stream>>>(flowf2, flowb2, img4_1, img4_2, part);

    finalize_kernel<<<1, threads, 0, stream>>>(part, (float*)d_out);
}

// Round 7
// 282.749 us; speedup vs baseline: 1.9132x; 1.3288x over previous
//
#include <hip/hip_runtime.h>
#include <math.h>

#define BATCH 8
#define IH 384
#define IW 512
#define NPIX (IH*IW)          // 196608
#define BN (BATCH*NPIX)       // 1572864

// Fused-kernel tiling: 64x16 output tile, +2 halo each side for the 5-tap filter
#define TW 64
#define TH 16
#define RW (TW+4)             // 68
#define RH (TH+4)             // 20
#define RN (RW*RH)            // 1360
#define NTX (IW/TW)           // 8
#define NTY (IH/TH)           // 24
#define NB_DIR (NTX*NTY*BATCH*2)   // 3072

#define NB_FLOW 1536
#define ENT_OFF NB_DIR                 // 3072
#define EPE_OFF (ENT_OFF + NB_FLOW)    // 4608
#define PART_FLOATS 8192

__device__ __forceinline__ float frcp_(float x){ return __builtin_amdgcn_rcpf(x); }
__device__ __forceinline__ float fsqrt_(float x){ return __builtin_amdgcn_sqrtf(x); }
__device__ __forceinline__ float sigmoidf_(float x){ return frcp_(1.0f + __expf(-x)); }

__device__ __forceinline__ float block_reduce_sum(float v){
    __shared__ float s[8];
    #pragma unroll
    for (int off=32; off>0; off>>=1) v += __shfl_down(v, off);
    int lane = threadIdx.x & 63, wid = threadIdx.x >> 6;
    if (lane==0) s[wid] = v;
    __syncthreads();
    float t = 0.f;
    if (wid==0){
        int nw = (blockDim.x+63)>>6;
        t = (lane < nw) ? s[lane] : 0.f;
        #pragma unroll
        for (int off=4; off>0; off>>=1) t += __shfl_down(t, off);
    }
    __syncthreads();
    return t;
}

// bilinear tap indices/weights; vin=0 zeroes all weights (out-of-image query pixel)
__device__ __forceinline__ void taps_(float Xp, float Yp, float vin, int idx[4], float wt[4]){
    float x0f = floorf(Xp), y0f = floorf(Yp);
    float wx1 = Xp-x0f, wy1 = Yp-y0f, wx0 = 1.f-wx1, wy0 = 1.f-wy1;
    float xs[4] = {x0f, x0f+1.f, x0f,      x0f+1.f};
    float ys[4] = {y0f, y0f,     y0f+1.f,  y0f+1.f};
    float wsx[4] = {wx0*wy0*vin, wx1*wy0*vin, wx0*wy1*vin, wx1*wy1*vin};
    #pragma unroll
    for (int k=0;k<4;++k){
        bool valid = (xs[k]>=0.f) & (xs[k]<=(float)(IW-1)) & (ys[k]>=0.f) & (ys[k]<=(float)(IH-1));
        float xc = fminf(fmaxf(xs[k],0.f),(float)(IW-1));
        float yc = fminf(fmaxf(ys[k],0.f),(float)(IH-1));
        idx[k] = (int)yc*IW + (int)xc;
        wt[k]  = valid ? wsx[k] : 0.f;
    }
}

// Prep: flows = mean + exp(lv/2)*noise (interleaved float2) + entropy/epe partials
//       + repack both images planar->pixel-major float4, all in one pass.
__global__ __launch_bounds__(256)
void prep_kernel(const float* __restrict__ meanf, const float* __restrict__ log_varf,
                 const float* __restrict__ meanb, const float* __restrict__ log_varb,
                 const float* __restrict__ target,
                 const float* __restrict__ noise_f, const float* __restrict__ noise_b,
                 const float* __restrict__ img1, const float* __restrict__ img2,
                 float2* __restrict__ flowf2, float2* __restrict__ flowb2,
                 float4* __restrict__ img4_1, float4* __restrict__ img4_2,
                 float* __restrict__ part)
{
    int t = blockIdx.x*blockDim.x + threadIdx.x;      // float4-group over (B, NPIX/4)
    const int NP4 = NPIX/4;
    int b = t / NP4, p4 = t - b*NP4;
    size_t i0 = ((size_t)b*2*NPIX)/4 + p4;
    size_t i1 = i0 + NP4;

    const float4* mf = (const float4*)meanf;  const float4* lf = (const float4*)log_varf;
    const float4* mb = (const float4*)meanb;  const float4* lb = (const float4*)log_varb;
    const float4* nf = (const float4*)noise_f; const float4* nb = (const float4*)noise_b;
    const float4* tg = (const float4*)target;

    float4 lf0 = lf[i0], lf1 = lf[i1], lb0 = lb[i0], lb1 = lb[i1];
    float4 mf0 = mf[i0], mf1 = mf[i1], mb0 = mb[i0], mb1 = mb[i1];
    float4 nf0 = nf[i0], nf1 = nf[i1], nb0 = nb[i0], nb1 = nb[i1];

    float4 fx, fy;
    fx.x = mf0.x + __expf(0.5f*lf0.x)*nf0.x; fx.y = mf0.y + __expf(0.5f*lf0.y)*nf0.y;
    fx.z = mf0.z + __expf(0.5f*lf0.z)*nf0.z; fx.w = mf0.w + __expf(0.5f*lf0.w)*nf0.w;
    fy.x = mf1.x + __expf(0.5f*lf1.x)*nf1.x; fy.y = mf1.y + __expf(0.5f*lf1.y)*nf1.y;
    fy.z = mf1.z + __expf(0.5f*lf1.z)*nf1.z; fy.w = mf1.w + __expf(0.5f*lf1.w)*nf1.w;
    float2* df = flowf2 + (size_t)b*NPIX + 4*(size_t)p4;
    df[0] = make_float2(fx.x, fy.x); df[1] = make_float2(fx.y, fy.y);
    df[2] = make_float2(fx.z, fy.z); df[3] = make_float2(fx.w, fy.w);

    fx.x = mb0.x + __expf(0.5f*lb0.x)*nb0.x; fx.y = mb0.y + __expf(0.5f*lb0.y)*nb0.y;
    fx.z = mb0.z + __expf(0.5f*lb0.z)*nb0.z; fx.w = mb0.w + __expf(0.5f*lb0.w)*nb0.w;
    fy.x = mb1.x + __expf(0.5f*lb1.x)*nb1.x; fy.y = mb1.y + __expf(0.5f*lb1.y)*nb1.y;
    fy.z = mb1.z + __expf(0.5f*lb1.z)*nb1.z; fy.w = mb1.w + __expf(0.5f*lb1.w)*nb1.w;
    float2* db = flowb2 + (size_t)b*NPIX + 4*(size_t)p4;
    db[0] = make_float2(fx.x, fy.x); db[1] = make_float2(fx.y, fy.y);
    db[2] = make_float2(fx.z, fy.z); db[3] = make_float2(fx.w, fy.w);

    // image repack
    {
        const float4* s1 = (const float4*)(img1 + (size_t)b*3*NPIX);
        float4 c0 = s1[p4], c1 = s1[NP4 + p4], c2 = s1[2*NP4 + p4];
        float4* d1 = img4_1 + (size_t)b*NPIX + 4*(size_t)p4;
        d1[0] = make_float4(c0.x, c1.x, c2.x, 0.f);
        d1[1] = make_float4(c0.y, c1.y, c2.y, 0.f);
        d1[2] = make_float4(c0.z, c1.z, c2.z, 0.f);
        d1[3] = make_float4(c0.w, c1.w, c2.w, 0.f);
        const float4* s2 = (const float4*)(img2 + (size_t)b*3*NPIX);
        c0 = s2[p4]; c1 = s2[NP4 + p4]; c2 = s2[2*NP4 + p4];
        float4* d2 = img4_2 + (size_t)b*NPIX + 4*(size_t)p4;
        d2[0] = make_float4(c0.x, c1.x, c2.x, 0.f);
        d2[1] = make_float4(c0.y, c1.y, c2.y, 0.f);
        d2[2] = make_float4(c0.z, c1.z, c2.z, 0.f);
        d2[3] = make_float4(c0.w, c1.w, c2.w, 0.f);
    }

    float ent = (lf0.x+lf0.y+lf0.z+lf0.w) + (lf1.x+lf1.y+lf1.z+lf1.w)
              + (lb0.x+lb0.y+lb0.z+lb0.w) + (lb1.x+lb1.y+lb1.z+lb1.w);

    float4 t0 = tg[i0], t1 = tg[i1];
    float d0, d1, epe = 0.f;
    d0 = mf0.x - t0.x; d1 = mf1.x - t1.x; epe += fsqrt_(d0*d0 + d1*d1);
    d0 = mf0.y - t0.y; d1 = mf1.y - t1.y; epe += fsqrt_(d0*d0 + d1*d1);
    d0 = mf0.z - t0.z; d1 = mf1.z - t1.z; epe += fsqrt_(d0*d0 + d1*d1);
    d0 = mf0.w - t0.w; d1 = mf1.w - t1.w; epe += fsqrt_(d0*d0 + d1*d1);

    float s = block_reduce_sum(ent);
    if (threadIdx.x == 0) part[ENT_OFF + blockIdx.x] = s;
    float s2 = block_reduce_sum(epe);
    if (threadIdx.x == 0) part[EPE_OFF + blockIdx.x] = s2;
}

// Fused per-direction tile kernel.
// SPILL HISTORY: R5 (256,8)+full-unroll -> 574MB scratch writes; R6 (256,4)+full-unroll
// -> 333MB. Full unroll of W(6)/T(4)/B(4) hoists 20-30 long-latency loads past the
// register budget. Fix: strided loops with unroll capped at 1-2 (R4-style, which
// measured VGPR=40, WRITE=101KB). No min-waves hint — let the allocator breathe.
__global__ __launch_bounds__(256)
void dir_kernel(const float2* __restrict__ flowf2, const float2* __restrict__ flowb2,
                const float4* __restrict__ img4_1, const float4* __restrict__ img4_2,
                float* __restrict__ part)
{
    __shared__ float wr[RH*RW], wg[RH*RW], wb[RH*RW];   // 3*5440 B
    __shared__ float ml[TH*TW];                          // 4096 B

    // XCD-aware decode: all 192 tiles of one (b,dir) land on one XCD (id%8 heuristic)
    int bx = blockIdx.x;
    int xcd = bx & 7, r = bx >> 3;          // r in [0,384)
    int half = (r >= 192) ? 1 : 0;
    int j = r - half*192;                   // tile in [0,192)
    int t = xcd + (half << 3);              // (b,dir) in [0,16)
    int dir = t & 1, b = t >> 1;
    int tx = j & 7, ty = j >> 3;

    const float2 *pfa, *pfb; const float4 *pia, *pib;
    if (dir == 0){ pfa = flowf2; pfb = flowb2; pia = img4_1; pib = img4_2; }
    else         { pfa = flowb2; pfb = flowf2; pia = img4_2; pib = img4_1; }
    pfa += (size_t)b*NPIX; pfb += (size_t)b*NPIX;
    pia += (size_t)b*NPIX; pib += (size_t)b*NPIX;

    const int tw0 = tx*TW, th0 = ty*TH;
    const int tid = threadIdx.x;
    float local = 0.f;

    // ---- Loop W: halo warp into LDS planes ----
    #pragma unroll 2
    for (int i = tid; i < RN; i += 256){
        int hh = i / RW, ww = i - hh*RW;
        int gh = th0 + hh - 2, gw = tw0 + ww - 2;
        bool inimg = (gh >= 0) & (gh < IH) & (gw >= 0) & (gw < IW);
        int pc = min(max(gh,0),IH-1)*IW + min(max(gw,0),IW-1);
        float2 fa = pfa[pc];
        float Xp = (float)gw + fa.x, Yp = (float)gh + fa.y;
        int idx[4]; float wt[4];
        taps_(Xp, Yp, inimg ? 1.f : 0.f, idx, wt);
        float4 t0 = pib[idx[0]], t1 = pib[idx[1]], t2 = pib[idx[2]], t3 = pib[idx[3]];
        wr[i] = wt[0]*t0.x + wt[1]*t1.x + wt[2]*t2.x + wt[3]*t3.x;
        wg[i] = wt[0]*t0.y + wt[1]*t1.y + wt[2]*t2.y + wt[3]*t3.y;
        wb[i] = wt[0]*t0.z + wt[1]*t1.z + wt[2]*t2.z + wt[3]*t3.z;
    }
    __syncthreads();

    // ---- Loop T: interior terms (1024 = 4*256, branch-free) ----
    #pragma unroll 1
    for (int i = tid; i < TW*TH; i += 256){
        int hh = i >> 6, ww = i & 63;
        int gh = th0 + hh, gw = tw0 + ww;
        int p = gh*IW + gw;
        float2 fa = pfa[p];                  // L1/L2 hit (loaded in loop W)
        float Xp = (float)gw + fa.x, Yp = (float)gh + fa.y;
        int idx[4]; float wt[4];
        taps_(Xp, Yp, 1.f, idx, wt);

        float2 f0 = pfb[idx[0]], f1 = pfb[idx[1]], f2 = pfb[idx[2]], f3 = pfb[idx[3]];
        float fbwx = wt[0]*f0.x + wt[1]*f1.x + wt[2]*f2.x + wt[3]*f3.x;
        float fbwy = wt[0]*f0.y + wt[1]*f1.y + wt[2]*f2.y + wt[3]*f3.y;

        float mx = sigmoidf_(Xp + 0.5f) * (1.f - sigmoidf_(Xp - ((float)IW - 0.5f)));
        float my = sigmoidf_(Yp + 0.5f) * (1.f - sigmoidf_(Yp - ((float)IH - 0.5f)));
        float bm = mx * my;

        float mag = fa.x*fa.x + fa.y*fa.y + fbwx*fbwx + fbwy*fbwy;
        float dfx = fa.x + fbwx, dfy = fa.y + fbwy;
        float D = dfx*dfx + dfy*dfy;
        float occ = 1.f - sigmoidf_(D - (0.01f*mag + 0.5f));
        float mask = bm * occ;
        ml[i] = mask;

        local += (1.f - mask);                            // mask term
        local += fsqrt_(D + 1e-5f) * mask;                // fb term

        int li = (hh+2)*RW + (ww+2);                      // data term (warp from LDS)
        float4 ia = pia[p];
        float d0 = ia.x - wr[li], d1 = ia.y - wg[li], d2 = ia.z - wb[li];
        local += fsqrt_(d0*d0 + d1*d1 + d2*d2 + 1e-5f) * mask;

        // smoothness: clamp-to-self makes the boundary diff exactly 0
        float2 rr = pfa[(gw < IW-1) ? (p+1)  : p];
        float2 dd = pfa[(gh < IH-1) ? (p+IW) : p];
        float e0 = rr.x - fa.x, e1 = rr.y - fa.y;
        float e2 = dd.x - fa.x, e3 = dd.y - fa.y;
        local += fsqrt_(e0*e0 + e1*e1 + e2*e2 + e3*e3 + 1e-5f);
    }
    __syncthreads();

    // ---- Loop B: gradient-constancy (1024 = 4*256, branch-free) ----
    const float K0 = -1.f/12.f, K1 = 2.f/3.f, K3 = -2.f/3.f, K4 = 1.f/12.f;
    const float4 Z = make_float4(0.f,0.f,0.f,0.f);
    #pragma unroll 2
    for (int i = tid; i < TW*TH; i += 256){
        int hh = i >> 6, ww = i & 63;
        int gh = th0 + hh, gw = tw0 + ww;
        int p = gh*IW + gw;
        int li = (hh+2)*RW + (ww+2);

        float4 axm2 = (gw >= 2)    ? pia[p-2]    : Z;
        float4 axm1 = (gw >= 1)    ? pia[p-1]    : Z;
        float4 axp1 = (gw <= IW-2) ? pia[p+1]    : Z;
        float4 axp2 = (gw <= IW-3) ? pia[p+2]    : Z;
        float4 aym2 = (gh >= 2)    ? pia[p-2*IW] : Z;
        float4 aym1 = (gh >= 1)    ? pia[p-IW]   : Z;
        float4 ayp1 = (gh <= IH-2) ? pia[p+IW]   : Z;
        float4 ayp2 = (gh <= IH-3) ? pia[p+2*IW] : Z;

        float Ct = 0.f, d;
        d = (K0*axm2.x + K1*axm1.x + K3*axp1.x + K4*axp2.x)
          - (K0*wr[li-2] + K1*wr[li-1] + K3*wr[li+1] + K4*wr[li+2]); Ct += d*d;
        d = (K0*axm2.y + K1*axm1.y + K3*axp1.y + K4*axp2.y)
          - (K0*wg[li-2] + K1*wg[li-1] + K3*wg[li+1] + K4*wg[li+2]); Ct += d*d;
        d = (K0*axm2.z + K1*axm1.z + K3*axp1.z + K4*axp2.z)
          - (K0*wb[li-2] + K1*wb[li-1] + K3*wb[li+1] + K4*wb[li+2]); Ct += d*d;
        d = (K0*aym2.x + K1*aym1.x + K3*ayp1.x + K4*ayp2.x)
          - (K0*wr[li-2*RW] + K1*wr[li-RW] + K3*wr[li+RW] + K4*wr[li+2*RW]); Ct += d*d;
        d = (K0*aym2.y + K1*aym1.y + K3*ayp1.y + K4*ayp2.y)
          - (K0*wg[li-2*RW] + K1*wg[li-RW] + K3*wg[li+RW] + K4*wg[li+2*RW]); Ct += d*d;
        d = (K0*aym2.z + K1*aym1.z + K3*ayp1.z + K4*ayp2.z)
          - (K0*wb[li-2*RW] + K1*wb[li-RW] + K3*wb[li+RW] + K4*wb[li+2*RW]); Ct += d*d;

        local += fsqrt_(Ct + 1e-5f) * ml[i];
    }

    float s = block_reduce_sum(local);
    if (tid == 0) part[bx] = s;
}

// Finalize: reduce all partials with one block.
__global__ __launch_bounds__(256)
void finalize_kernel(const float* __restrict__ part, float* __restrict__ out)
{
    float e = 0.f, ent = 0.f, epe = 0.f;
    for (int i = threadIdx.x; i < NB_DIR; i += 256) e += part[i];
    for (int i = threadIdx.x; i < NB_FLOW; i += 256){
        ent += part[ENT_OFF + i];
        epe += part[EPE_OFF + i];
    }
    e   = block_reduce_sum(e);
    ent = block_reduce_sum(ent);
    epe = block_reduce_sum(epe);
    if (threadIdx.x == 0){
        out[0] = e / (float)BATCH - ent / (2.f * (float)BATCH);
        out[1] = epe / ((float)BATCH * (float)NPIX);
    }
}

extern "C" void kernel_launch(void* const* d_in, const int* in_sizes, int n_in,
                              void* d_out, int out_size, void* d_ws, size_t ws_size,
                              hipStream_t stream)
{
    const float* meanf    = (const float*)d_in[0];
    const float* log_varf = (const float*)d_in[1];
    const float* meanb    = (const float*)d_in[2];
    const float* log_varb = (const float*)d_in[3];
    const float* img1     = (const float*)d_in[4];
    const float* img2     = (const float*)d_in[5];
    const float* target   = (const float*)d_in[6];
    const float* noise_f  = (const float*)d_in[7];
    const float* noise_b  = (const float*)d_in[8];

    float*  ws     = (float*)d_ws;
    float*  part   = ws;                               // PART_FLOATS floats
    float2* flowf2 = (float2*)(ws + PART_FLOATS);      // BN float2
    float2* flowb2 = flowf2 + (size_t)BN;              // BN float2
    float4* img4_1 = (float4*)(flowb2 + (size_t)BN);   // BN float4
    float4* img4_2 = img4_1 + (size_t)BN;              // BN float4

    const int threads = 256;

    prep_kernel<<<NB_FLOW, threads, 0, stream>>>(meanf, log_varf, meanb, log_varb,
                                                 target, noise_f, noise_b, img1, img2,
                                                 flowf2, flowb2, img4_1, img4_2, part);

    dir_kernel<<<NB_DIR, threads, 0, stream>>>(flowf2, flowb2, img4_1, img4_2, part);

    finalize_kernel<<<1, threads, 0, stream>>>(part, (float*)d_out);
}